// Round 1
// baseline (4302.427 us; speedup 1.0000x reference)
//
#include <hip/hip_runtime.h>

#define BN_EPS 1e-5f
#define TN 128     // nodes per MLP block
#define CHUNK 32   // nodes per wave in bnpool

// ---------------- scatter: sumbuf[dst] += h[src], 16 threads (float4 lanes) per edge ----
__global__ __launch_bounds__(256) void scatter_kernel(
    const float* __restrict__ hin, const int* __restrict__ src,
    const int* __restrict__ dst, float* __restrict__ sumbuf, int E)
{
    int gid = blockIdx.x * 256 + threadIdx.x;
    int e = gid >> 4;
    if (e >= E) return;
    int c = (gid & 15) * 4;
    int s = src[e], d = dst[e];
    const float4 v = *reinterpret_cast<const float4*>(hin + (size_t)s * 64 + c);
    float* p = sumbuf + (size_t)d * 64 + c;
    atomicAdd(p + 0, v.x);
    atomicAdd(p + 1, v.y);
    atomicAdd(p + 2, v.z);
    atomicAdd(p + 3, v.w);
}

// ---------------- fused MLP: z = relu(relu((h+sum)@W1+b1)@W2+b2), + BN partial sums ----
__global__ __launch_bounds__(256) void mlp_kernel(
    const float* __restrict__ hin, const float* __restrict__ sumbuf,
    const float* __restrict__ w1, const float* __restrict__ b1,
    const float* __restrict__ w2, const float* __restrict__ b2,
    float* __restrict__ zout, float* __restrict__ bnstats, int layer, int nN)
{
    __shared__ float sW1[64 * 64];
    __shared__ float sW2[64 * 64];
    __shared__ float sA[64 * 132];          // transposed A / T tile, padded rows
    __shared__ float sB1[64], sB2[64], sSum[64], sSq[64];
    const int tid = threadIdx.x;

    const float4* w1v = reinterpret_cast<const float4*>(w1 + (size_t)layer * 4096);
    const float4* w2v = reinterpret_cast<const float4*>(w2 + (size_t)layer * 4096);
    float4* sW1v = reinterpret_cast<float4*>(sW1);
    float4* sW2v = reinterpret_cast<float4*>(sW2);
    for (int i = tid; i < 1024; i += 256) { sW1v[i] = w1v[i]; sW2v[i] = w2v[i]; }
    if (tid < 64) {
        sB1[tid] = b1[layer * 64 + tid];
        sB2[tid] = b2[layer * 64 + tid];
        sSum[tid] = 0.f; sSq[tid] = 0.f;
    }

    const int n0 = blockIdx.x * TN;
    // stage A = hin + sumbuf, transposed into sA[k*132 + n]
    for (int i = tid; i < TN * 16; i += 256) {
        const int n = i >> 4;
        const int k4 = i & 15;
        const int node = n0 + n;
        float4 v = make_float4(0.f, 0.f, 0.f, 0.f);
        if (node < nN) {
            const float4 a = *reinterpret_cast<const float4*>(hin + (size_t)node * 64 + k4 * 4);
            const float4 s = *reinterpret_cast<const float4*>(sumbuf + (size_t)node * 64 + k4 * 4);
            v = make_float4(a.x + s.x, a.y + s.y, a.z + s.z, a.w + s.w);
        }
        const int k = k4 * 4;
        sA[(k + 0) * 132 + n] = v.x;
        sA[(k + 1) * 132 + n] = v.y;
        sA[(k + 2) * 132 + n] = v.z;
        sA[(k + 3) * 132 + n] = v.w;
    }
    __syncthreads();

    const int jq = tid & 15;   // j-quad: features jq*4 .. jq*4+3
    const int no = tid >> 4;   // node-octet: nodes no*8 .. no*8+7
    float acc[8][4];

    // ---- mm1: T = relu(A @ W1 + b1) ----
#pragma unroll
    for (int nn = 0; nn < 8; ++nn)
#pragma unroll
        for (int jj = 0; jj < 4; ++jj) acc[nn][jj] = sB1[jq * 4 + jj];
#pragma unroll 4
    for (int k = 0; k < 64; ++k) {
        const float4 a0 = *reinterpret_cast<const float4*>(&sA[k * 132 + no * 8]);
        const float4 a1 = *reinterpret_cast<const float4*>(&sA[k * 132 + no * 8 + 4]);
        const float4 wv = *reinterpret_cast<const float4*>(&sW1[k * 64 + jq * 4]);
        const float av[8] = {a0.x, a0.y, a0.z, a0.w, a1.x, a1.y, a1.z, a1.w};
        const float wj[4] = {wv.x, wv.y, wv.z, wv.w};
#pragma unroll
        for (int nn = 0; nn < 8; ++nn)
#pragma unroll
            for (int jj = 0; jj < 4; ++jj) acc[nn][jj] = fmaf(av[nn], wj[jj], acc[nn][jj]);
    }
    __syncthreads();   // all threads done reading A tile
    // write T transposed (with relu) into sA[j*132 + n]
#pragma unroll
    for (int nn = 0; nn < 8; ++nn)
#pragma unroll
        for (int jj = 0; jj < 4; ++jj)
            sA[(jq * 4 + jj) * 132 + no * 8 + nn] = fmaxf(acc[nn][jj], 0.f);
    __syncthreads();

    // ---- mm2: Z = relu(T @ W2 + b2) ----
#pragma unroll
    for (int nn = 0; nn < 8; ++nn)
#pragma unroll
        for (int jj = 0; jj < 4; ++jj) acc[nn][jj] = sB2[jq * 4 + jj];
#pragma unroll 4
    for (int k = 0; k < 64; ++k) {
        const float4 a0 = *reinterpret_cast<const float4*>(&sA[k * 132 + no * 8]);
        const float4 a1 = *reinterpret_cast<const float4*>(&sA[k * 132 + no * 8 + 4]);
        const float4 wv = *reinterpret_cast<const float4*>(&sW2[k * 64 + jq * 4]);
        const float av[8] = {a0.x, a0.y, a0.z, a0.w, a1.x, a1.y, a1.z, a1.w};
        const float wj[4] = {wv.x, wv.y, wv.z, wv.w};
#pragma unroll
        for (int nn = 0; nn < 8; ++nn)
#pragma unroll
            for (int jj = 0; jj < 4; ++jj) acc[nn][jj] = fmaf(av[nn], wj[jj], acc[nn][jj]);
    }

    // relu + store + BN partials (valid nodes only)
#pragma unroll
    for (int nn = 0; nn < 8; ++nn) {
        const int node = n0 + no * 8 + nn;
#pragma unroll
        for (int jj = 0; jj < 4; ++jj) acc[nn][jj] = fmaxf(acc[nn][jj], 0.f);
        if (node < nN) {
            *reinterpret_cast<float4*>(zout + (size_t)node * 64 + jq * 4) =
                make_float4(acc[nn][0], acc[nn][1], acc[nn][2], acc[nn][3]);
        }
    }
#pragma unroll
    for (int jj = 0; jj < 4; ++jj) {
        float s = 0.f, q = 0.f;
#pragma unroll
        for (int nn = 0; nn < 8; ++nn) {
            const int node = n0 + no * 8 + nn;
            if (node < nN) { const float v = acc[nn][jj]; s += v; q += v * v; }
        }
        atomicAdd(&sSum[jq * 4 + jj], s);
        atomicAdd(&sSq[jq * 4 + jj], q);
    }
    __syncthreads();
    if (tid < 64) {
        atomicAdd(&bnstats[tid], sSum[tid]);
        atomicAdd(&bnstats[64 + tid], sSq[tid]);
    }
}

// ---------------- BN apply + write h + pooled segment-sum into xp ----
__global__ __launch_bounds__(256) void bnpool_kernel(
    const float* __restrict__ z, const float* __restrict__ bnstats,
    const float* __restrict__ gamma, const float* __restrict__ beta,
    const int* __restrict__ batch, float* __restrict__ h,
    float* __restrict__ xp, int layer, int nN)
{
    const int wave = (blockIdx.x * 256 + threadIdx.x) >> 6;
    const int d = threadIdx.x & 63;
    const int start = wave * CHUNK;
    if (start >= nN) return;
    const int end = min(start + CHUNK, nN);
    const float invN = 1.0f / (float)nN;
    const float mean = bnstats[d] * invN;
    const float var = fmaxf(bnstats[64 + d] * invN - mean * mean, 0.f);
    const float sc = gamma[layer * 64 + d] * rsqrtf(var + BN_EPS);
    const float sh = beta[layer * 64 + d] - mean * sc;

    float accp = 0.f;
    int cur = batch[start];
    for (int n = start; n < end; ++n) {
        const float v = fmaf(z[(size_t)n * 64 + d], sc, sh);
        h[(size_t)n * 64 + d] = v;
        const int g = batch[n];
        if (g != cur) {
            atomicAdd(&xp[(size_t)cur * 192 + layer * 64 + d], accp);
            accp = 0.f; cur = g;
        }
        accp += v;
    }
    atomicAdd(&xp[(size_t)cur * 192 + layer * 64 + d], accp);
}

// ---------------- head: out = log_softmax(relu(xp @ lin_w + lin_b) @ fin_w + fin_b) ----
__global__ __launch_bounds__(256) void final_kernel(
    const float* __restrict__ xp, const float* __restrict__ lin_w,
    const float* __restrict__ lin_b, const float* __restrict__ fin_w,
    const float* __restrict__ fin_b, float* __restrict__ out, int nG)
{
    const int g = (blockIdx.x * 256 + threadIdx.x) >> 6;
    const int lane = threadIdx.x & 63;
    if (g >= nG) return;
    const float* xr = xp + (size_t)g * 192;
    float acc = lin_b[lane];
    for (int k = 0; k < 192; ++k) acc = fmaf(xr[k], lin_w[k * 64 + lane], acc);
    const float t = fmaxf(acc, 0.f);
    float o[10];
#pragma unroll
    for (int c = 0; c < 10; ++c) {
        float p = t * fin_w[lane * 10 + c];
#pragma unroll
        for (int off = 32; off > 0; off >>= 1) p += __shfl_xor(p, off);
        o[c] = p + fin_b[c];
    }
    float m = o[0];
#pragma unroll
    for (int c = 1; c < 10; ++c) m = fmaxf(m, o[c]);
    float Z = 0.f;
#pragma unroll
    for (int c = 0; c < 10; ++c) Z += expf(o[c] - m);
    const float lz = m + logf(Z);
#pragma unroll
    for (int c = 0; c < 10; ++c)
        if (lane == c) out[(size_t)g * 10 + c] = o[c] - lz;
}

extern "C" void kernel_launch(void* const* d_in, const int* in_sizes, int n_in,
                              void* d_out, int out_size, void* d_ws, size_t ws_size,
                              hipStream_t stream)
{
    const float* x     = (const float*)d_in[0];
    const int*   ei    = (const int*)d_in[1];
    const int*   batch = (const int*)d_in[2];
    const float* w1    = (const float*)d_in[3];
    const float* b1    = (const float*)d_in[4];
    const float* w2    = (const float*)d_in[5];
    const float* b2    = (const float*)d_in[6];
    const float* gamma = (const float*)d_in[7];
    const float* beta  = (const float*)d_in[8];
    const float* lin_w = (const float*)d_in[9];
    const float* lin_b = (const float*)d_in[10];
    const float* fin_w = (const float*)d_in[11];
    const float* fin_b = (const float*)d_in[12];
    float* out = (float*)d_out;

    const int N = in_sizes[0] / 64;
    const int E = in_sizes[1] / 2;
    const int L = in_sizes[3] / 4096;
    const int G = out_size / 10;

    char* ws = (char*)d_ws;
    size_t off = 0;
    auto alloc = [&](size_t bytes) -> void* {
        void* p = ws + off;
        off += (bytes + 255) & ~(size_t)255;
        return p;
    };
    float* sumbuf  = (float*)alloc((size_t)N * 64 * 4);
    float* zbuf    = (float*)alloc((size_t)N * 64 * 4);
    float* hbuf    = (float*)alloc((size_t)N * 64 * 4);
    float* xp      = (float*)alloc((size_t)G * 192 * 4);
    float* bnstats = (float*)alloc(128 * 4);

    hipMemsetAsync(xp, 0, (size_t)G * 192 * 4, stream);

    const int* srcIdx = ei;
    const int* dstIdx = ei + E;

    const float* hin = x;
    for (int l = 0; l < L; ++l) {
        hipMemsetAsync(sumbuf, 0, (size_t)N * 64 * 4, stream);
        hipMemsetAsync(bnstats, 0, 128 * 4, stream);

        {
            const long long tot = (long long)E * 16;
            const int blocks = (int)((tot + 255) / 256);
            scatter_kernel<<<blocks, 256, 0, stream>>>(hin, srcIdx, dstIdx, sumbuf, E);
        }
        {
            const int blocks = (N + TN - 1) / TN;
            mlp_kernel<<<blocks, 256, 0, stream>>>(hin, sumbuf, w1, b1, w2, b2,
                                                   zbuf, bnstats, l, N);
        }
        {
            const int waves = (N + CHUNK - 1) / CHUNK;
            const int blocks = (waves * 64 + 255) / 256;
            bnpool_kernel<<<blocks, 256, 0, stream>>>(zbuf, bnstats, gamma, beta,
                                                      batch, hbuf, xp, l, N);
        }
        hin = hbuf;
    }
    final_kernel<<<(G * 64 + 255) / 256, 256, 0, stream>>>(xp, lin_w, lin_b,
                                                           fin_w, fin_b, out, G);
}

// Round 2
// 620.242 us; speedup vs baseline: 6.9367x; 6.9367x over previous
//
#include <hip/hip_runtime.h>

#define BN_EPS 1e-5f
#define TN 128      // nodes per MLP block
#define CHUNK 32    // nodes per wave in bnpool
#define SCAN_BS 1024 // elements per scan block (256 thr x 4)

// ============ CSR build ============
__global__ __launch_bounds__(256) void deg_kernel(
    const int* __restrict__ dst, int* __restrict__ deg, int E)
{
    int e = blockIdx.x * 256 + threadIdx.x;
    if (e < E) atomicAdd(&deg[dst[e]], 1);
}

__global__ __launch_bounds__(256) void scan_part_kernel(
    const int* __restrict__ deg, int* __restrict__ rowstart,
    int* __restrict__ blocksum, int nN)
{
    __shared__ int lsum[256];
    const int t = threadIdx.x;
    const int base = blockIdx.x * SCAN_BS + t * 4;
    int v[4]; int s = 0;
#pragma unroll
    for (int k = 0; k < 4; ++k) {
        const int idx = base + k;
        v[k] = (idx < nN) ? deg[idx] : 0;
        s += v[k];
    }
    lsum[t] = s;
    __syncthreads();
    for (int off = 1; off < 256; off <<= 1) {
        const int x = lsum[t];
        const int y = (t >= off) ? lsum[t - off] : 0;
        __syncthreads();
        lsum[t] = x + y;
        __syncthreads();
    }
    int run = lsum[t] - s;   // exclusive prefix of this thread's 4 elems
#pragma unroll
    for (int k = 0; k < 4; ++k) {
        const int idx = base + k;
        if (idx < nN) rowstart[idx] = run;
        run += v[k];
    }
    if (t == 255) blocksum[blockIdx.x] = lsum[255];
}

__global__ void scan_top_kernel(int* __restrict__ blocksum,
                                int* __restrict__ blockoff, int nblk)
{
    if (threadIdx.x == 0 && blockIdx.x == 0) {
        int run = 0;
        for (int i = 0; i < nblk; ++i) { blockoff[i] = run; run += blocksum[i]; }
    }
}

__global__ __launch_bounds__(256) void scan_add_kernel(
    int* __restrict__ rowstart, int* __restrict__ cursor,
    const int* __restrict__ blockoff, int nN)
{
    const int i = blockIdx.x * 256 + threadIdx.x;
    if (i < nN) {
        const int r = rowstart[i] + blockoff[i / SCAN_BS];
        rowstart[i] = r;
        cursor[i] = r;
    }
}

__global__ __launch_bounds__(256) void fill_kernel(
    const int* __restrict__ src, const int* __restrict__ dst,
    int* __restrict__ cursor, int* __restrict__ eidx, int E)
{
    const int e = blockIdx.x * 256 + threadIdx.x;
    if (e < E) {
        const int p = atomicAdd(&cursor[dst[e]], 1);
        eidx[p] = src[e];
    }
}

// ============ aggregation: agg[n] = h[n] + sum_{s in in(n)} h[s] ============
__global__ __launch_bounds__(256) void agg_kernel(
    const float* __restrict__ h, const int* __restrict__ rowstart,
    const int* __restrict__ deg, const int* __restrict__ eidx,
    float* __restrict__ agg, int nN)
{
    const int node = blockIdx.x * 4 + (threadIdx.x >> 6);
    const int lane = threadIdx.x & 63;
    if (node >= nN) return;
    float acc = h[(size_t)node * 64 + lane];
    const int rs = rowstart[node];
    const int d = deg[node];
    int i = 0;
    for (; i + 4 <= d; i += 4) {
        const int s0 = eidx[rs + i + 0];
        const int s1 = eidx[rs + i + 1];
        const int s2 = eidx[rs + i + 2];
        const int s3 = eidx[rs + i + 3];
        const float v0 = h[(size_t)s0 * 64 + lane];
        const float v1 = h[(size_t)s1 * 64 + lane];
        const float v2 = h[(size_t)s2 * 64 + lane];
        const float v3 = h[(size_t)s3 * 64 + lane];
        acc += v0; acc += v1; acc += v2; acc += v3;
    }
    for (; i < d; ++i) acc += h[(size_t)eidx[rs + i] * 64 + lane];
    agg[(size_t)node * 64 + lane] = acc;
}

// ============ fused MLP: z = relu(relu(agg@W1+b1)@W2+b2), + BN partial sums ============
__global__ __launch_bounds__(256) void mlp_kernel(
    const float* __restrict__ agg,
    const float* __restrict__ w1, const float* __restrict__ b1,
    const float* __restrict__ w2, const float* __restrict__ b2,
    float* __restrict__ zout, float* __restrict__ bnstats, int layer, int nN)
{
    __shared__ float sW1[64 * 64];
    __shared__ float sW2[64 * 64];
    __shared__ float sA[64 * 132];
    __shared__ float sB1[64], sB2[64], sSum[64], sSq[64];
    const int tid = threadIdx.x;

    const float4* w1v = reinterpret_cast<const float4*>(w1 + (size_t)layer * 4096);
    const float4* w2v = reinterpret_cast<const float4*>(w2 + (size_t)layer * 4096);
    float4* sW1v = reinterpret_cast<float4*>(sW1);
    float4* sW2v = reinterpret_cast<float4*>(sW2);
    for (int i = tid; i < 1024; i += 256) { sW1v[i] = w1v[i]; sW2v[i] = w2v[i]; }
    if (tid < 64) {
        sB1[tid] = b1[layer * 64 + tid];
        sB2[tid] = b2[layer * 64 + tid];
        sSum[tid] = 0.f; sSq[tid] = 0.f;
    }

    const int n0 = blockIdx.x * TN;
    for (int i = tid; i < TN * 16; i += 256) {
        const int n = i >> 4;
        const int k4 = i & 15;
        const int node = n0 + n;
        float4 v = make_float4(0.f, 0.f, 0.f, 0.f);
        if (node < nN)
            v = *reinterpret_cast<const float4*>(agg + (size_t)node * 64 + k4 * 4);
        const int k = k4 * 4;
        sA[(k + 0) * 132 + n] = v.x;
        sA[(k + 1) * 132 + n] = v.y;
        sA[(k + 2) * 132 + n] = v.z;
        sA[(k + 3) * 132 + n] = v.w;
    }
    __syncthreads();

    const int jq = tid & 15;
    const int no = tid >> 4;
    float acc[8][4];

#pragma unroll
    for (int nn = 0; nn < 8; ++nn)
#pragma unroll
        for (int jj = 0; jj < 4; ++jj) acc[nn][jj] = sB1[jq * 4 + jj];
#pragma unroll 4
    for (int k = 0; k < 64; ++k) {
        const float4 a0 = *reinterpret_cast<const float4*>(&sA[k * 132 + no * 8]);
        const float4 a1 = *reinterpret_cast<const float4*>(&sA[k * 132 + no * 8 + 4]);
        const float4 wv = *reinterpret_cast<const float4*>(&sW1[k * 64 + jq * 4]);
        const float av[8] = {a0.x, a0.y, a0.z, a0.w, a1.x, a1.y, a1.z, a1.w};
        const float wj[4] = {wv.x, wv.y, wv.z, wv.w};
#pragma unroll
        for (int nn = 0; nn < 8; ++nn)
#pragma unroll
            for (int jj = 0; jj < 4; ++jj) acc[nn][jj] = fmaf(av[nn], wj[jj], acc[nn][jj]);
    }
    __syncthreads();
#pragma unroll
    for (int nn = 0; nn < 8; ++nn)
#pragma unroll
        for (int jj = 0; jj < 4; ++jj)
            sA[(jq * 4 + jj) * 132 + no * 8 + nn] = fmaxf(acc[nn][jj], 0.f);
    __syncthreads();

#pragma unroll
    for (int nn = 0; nn < 8; ++nn)
#pragma unroll
        for (int jj = 0; jj < 4; ++jj) acc[nn][jj] = sB2[jq * 4 + jj];
#pragma unroll 4
    for (int k = 0; k < 64; ++k) {
        const float4 a0 = *reinterpret_cast<const float4*>(&sA[k * 132 + no * 8]);
        const float4 a1 = *reinterpret_cast<const float4*>(&sA[k * 132 + no * 8 + 4]);
        const float4 wv = *reinterpret_cast<const float4*>(&sW2[k * 64 + jq * 4]);
        const float av[8] = {a0.x, a0.y, a0.z, a0.w, a1.x, a1.y, a1.z, a1.w};
        const float wj[4] = {wv.x, wv.y, wv.z, wv.w};
#pragma unroll
        for (int nn = 0; nn < 8; ++nn)
#pragma unroll
            for (int jj = 0; jj < 4; ++jj) acc[nn][jj] = fmaf(av[nn], wj[jj], acc[nn][jj]);
    }

#pragma unroll
    for (int nn = 0; nn < 8; ++nn) {
        const int node = n0 + no * 8 + nn;
#pragma unroll
        for (int jj = 0; jj < 4; ++jj) acc[nn][jj] = fmaxf(acc[nn][jj], 0.f);
        if (node < nN) {
            *reinterpret_cast<float4*>(zout + (size_t)node * 64 + jq * 4) =
                make_float4(acc[nn][0], acc[nn][1], acc[nn][2], acc[nn][3]);
        }
    }
#pragma unroll
    for (int jj = 0; jj < 4; ++jj) {
        float s = 0.f, q = 0.f;
#pragma unroll
        for (int nn = 0; nn < 8; ++nn) {
            const int node = n0 + no * 8 + nn;
            if (node < nN) { const float v = acc[nn][jj]; s += v; q += v * v; }
        }
        atomicAdd(&sSum[jq * 4 + jj], s);
        atomicAdd(&sSq[jq * 4 + jj], q);
    }
    __syncthreads();
    if (tid < 64) {
        atomicAdd(&bnstats[tid], sSum[tid]);
        atomicAdd(&bnstats[64 + tid], sSq[tid]);
    }
}

// ============ BN apply + write h + pooled segment-sum into xp ============
__global__ __launch_bounds__(256) void bnpool_kernel(
    const float* __restrict__ z, const float* __restrict__ bnstats,
    const float* __restrict__ gamma, const float* __restrict__ beta,
    const int* __restrict__ batch, float* __restrict__ h,
    float* __restrict__ xp, int layer, int nN)
{
    const int wave = (blockIdx.x * 256 + threadIdx.x) >> 6;
    const int d = threadIdx.x & 63;
    const int start = wave * CHUNK;
    if (start >= nN) return;
    const int end = min(start + CHUNK, nN);
    const float invN = 1.0f / (float)nN;
    const float mean = bnstats[d] * invN;
    const float var = fmaxf(bnstats[64 + d] * invN - mean * mean, 0.f);
    const float sc = gamma[layer * 64 + d] * rsqrtf(var + BN_EPS);
    const float sh = beta[layer * 64 + d] - mean * sc;

    float accp = 0.f;
    int cur = batch[start];
    for (int n = start; n < end; ++n) {
        const float v = fmaf(z[(size_t)n * 64 + d], sc, sh);
        h[(size_t)n * 64 + d] = v;
        const int g = batch[n];
        if (g != cur) {
            atomicAdd(&xp[(size_t)cur * 192 + layer * 64 + d], accp);
            accp = 0.f; cur = g;
        }
        accp += v;
    }
    atomicAdd(&xp[(size_t)cur * 192 + layer * 64 + d], accp);
}

// ============ head ============
__global__ __launch_bounds__(256) void final_kernel(
    const float* __restrict__ xp, const float* __restrict__ lin_w,
    const float* __restrict__ lin_b, const float* __restrict__ fin_w,
    const float* __restrict__ fin_b, float* __restrict__ out, int nG)
{
    const int g = (blockIdx.x * 256 + threadIdx.x) >> 6;
    const int lane = threadIdx.x & 63;
    if (g >= nG) return;
    const float* xr = xp + (size_t)g * 192;
    float acc = lin_b[lane];
    for (int k = 0; k < 192; ++k) acc = fmaf(xr[k], lin_w[k * 64 + lane], acc);
    const float t = fmaxf(acc, 0.f);
    float o[10];
#pragma unroll
    for (int c = 0; c < 10; ++c) {
        float p = t * fin_w[lane * 10 + c];
#pragma unroll
        for (int off = 32; off > 0; off >>= 1) p += __shfl_xor(p, off);
        o[c] = p + fin_b[c];
    }
    float m = o[0];
#pragma unroll
    for (int c = 1; c < 10; ++c) m = fmaxf(m, o[c]);
    float Z = 0.f;
#pragma unroll
    for (int c = 0; c < 10; ++c) Z += expf(o[c] - m);
    const float lz = m + logf(Z);
#pragma unroll
    for (int c = 0; c < 10; ++c)
        if (lane == c) out[(size_t)g * 10 + c] = o[c] - lz;
}

extern "C" void kernel_launch(void* const* d_in, const int* in_sizes, int n_in,
                              void* d_out, int out_size, void* d_ws, size_t ws_size,
                              hipStream_t stream)
{
    const float* x     = (const float*)d_in[0];
    const int*   ei    = (const int*)d_in[1];
    const int*   batch = (const int*)d_in[2];
    const float* w1    = (const float*)d_in[3];
    const float* b1    = (const float*)d_in[4];
    const float* w2    = (const float*)d_in[5];
    const float* b2    = (const float*)d_in[6];
    const float* gamma = (const float*)d_in[7];
    const float* beta  = (const float*)d_in[8];
    const float* lin_w = (const float*)d_in[9];
    const float* lin_b = (const float*)d_in[10];
    const float* fin_w = (const float*)d_in[11];
    const float* fin_b = (const float*)d_in[12];
    float* out = (float*)d_out;

    const int N = in_sizes[0] / 64;
    const int E = in_sizes[1] / 2;
    const int L = in_sizes[3] / 4096;
    const int G = out_size / 10;

    char* ws = (char*)d_ws;
    size_t off = 0;
    auto alloc = [&](size_t bytes) -> void* {
        void* p = ws + off;
        off += (bytes + 255) & ~(size_t)255;
        return p;
    };
    float* aggbuf  = (float*)alloc((size_t)N * 64 * 4);
    float* zbuf    = (float*)alloc((size_t)N * 64 * 4);
    float* hbuf    = (float*)alloc((size_t)N * 64 * 4);
    float* xp      = (float*)alloc((size_t)G * 192 * 4);
    float* bnstats = (float*)alloc(128 * 4);
    int*   deg      = (int*)alloc((size_t)N * 4);
    int*   rowstart = (int*)alloc((size_t)N * 4);
    int*   cursor   = (int*)alloc((size_t)N * 4);
    int*   eidx     = (int*)alloc((size_t)E * 4);
    int*   blocksum = (int*)alloc(256 * 4);
    int*   blockoff = (int*)alloc(256 * 4);

    const int* srcIdx = ei;
    const int* dstIdx = ei + E;

    // ---- CSR build (once; edges shared across layers) ----
    hipMemsetAsync(deg, 0, (size_t)N * 4, stream);
    hipMemsetAsync(xp, 0, (size_t)G * 192 * 4, stream);
    deg_kernel<<<(E + 255) / 256, 256, 0, stream>>>(dstIdx, deg, E);
    const int nblk = (N + SCAN_BS - 1) / SCAN_BS;
    scan_part_kernel<<<nblk, 256, 0, stream>>>(deg, rowstart, blocksum, N);
    scan_top_kernel<<<1, 64, 0, stream>>>(blocksum, blockoff, nblk);
    scan_add_kernel<<<(N + 255) / 256, 256, 0, stream>>>(rowstart, cursor, blockoff, N);
    fill_kernel<<<(E + 255) / 256, 256, 0, stream>>>(srcIdx, dstIdx, cursor, eidx, E);

    const float* hin = x;
    for (int l = 0; l < L; ++l) {
        hipMemsetAsync(bnstats, 0, 128 * 4, stream);
        agg_kernel<<<(N + 3) / 4, 256, 0, stream>>>(hin, rowstart, deg, eidx, aggbuf, N);
        mlp_kernel<<<(N + TN - 1) / TN, 256, 0, stream>>>(aggbuf, w1, b1, w2, b2,
                                                          zbuf, bnstats, l, N);
        {
            const int waves = (N + CHUNK - 1) / CHUNK;
            bnpool_kernel<<<(waves * 64 + 255) / 256, 256, 0, stream>>>(
                zbuf, bnstats, gamma, beta, batch, hbuf, xp, l, N);
        }
        hin = hbuf;
    }
    final_kernel<<<(G * 64 + 255) / 256, 256, 0, stream>>>(xp, lin_w, lin_b,
                                                           fin_w, fin_b, out, G);
}